// Round 1
// baseline (127.426 us; speedup 1.0000x reference)
//
#include <hip/hip_runtime.h>
#include <math.h>

// (B,P,V,F,H) = (32,512,32,16,64). Round 6: occupancy + VALU diet.
// - Single LDS x-buffer per wave (was double): all epilogue ds_writes
//   data-depend on the prior layerK ds_reads (acc <- MFMA <- a-frags), and
//   same-wave DS ops execute in order, so reuse is safe without barriers.
//   LDS 37888 -> 18944 B => 8 blocks/CU (32 waves/CU) instead of 4.
// - __launch_bounds__(256, 8): cap VGPR at 64 for 8 waves/SIMD. To fit:
//   a-frag ds_reads moved INSIDE the ks loop (each frag feeds exactly one
//   ks step; holding all 6 upfront = 24 live VGPRs), bias2/3 loaded late.
// - VALU diet: final output depends ONLY on pools (z[:,:,0,-H:] = pool3),
//   and pools exclude masked rows, so the per-element out-mask select is
//   dropped (unmasked lrelu written to LDS; masked rows never surface).
//   Pool masking via precomputed addm[i] = mk ? 0 : -inf => max(pv,y+addm).
//   f32->bf16 via v_cvt_pk_bf16_f32 (1 op / 2 elems) instead of 3-op bfrne.
// MFMA 16x16x32 bf16: A[m=lane&15][k=quad*8+j], B[k=quad*8+j][n=lane&15],
//                     D[row=quad*4+reg][col=lane&15]  (verified rounds 2-4).
namespace {
constexpr int kXS = 72;
constexpr float kSlope = 0.01f;

typedef short bf16x8 __attribute__((ext_vector_type(8)));
typedef float f32x4  __attribute__((ext_vector_type(4)));

__device__ __forceinline__ float lrelu(float x) { return fmaxf(x, kSlope * x); }

// 3-instruction round-to-nearest-even f32->bf16 (prep kernel only).
__device__ __forceinline__ unsigned short bfrne(float a) {
    union { float f; unsigned u; } v; v.f = a;
    return (unsigned short)((v.u + 0x7FFFu + ((v.u >> 16) & 1u)) >> 16);
}

// packed 2x f32 -> 2x bf16 (RNE), single VALU op. Non-volatile so the
// scheduler may move/CSE it freely.
__device__ __forceinline__ unsigned cvtpk(float lo, float hi) {
    unsigned r;
    asm("v_cvt_pk_bf16_f32 %0, %1, %2" : "=v"(r) : "v"(lo), "v"(hi));
    return r;
}

// ---- pre-pass: pack W1/W2/W3 as bf16 MFMA B-frags into d_ws ----
// frag f: 0..3 = W1 (nt=f, K=16 zero-padded); 4..19 = W2 (nt=(f-4)>>2,
// ks=(f-4)&3); 20..35 = W3. Lane l of frag f lives at ws[f*512 + l*8 ..+7].
__global__ void prep_weights(const float* __restrict__ W1,
                             const float* __restrict__ W2,
                             const float* __restrict__ W3,
                             unsigned short* __restrict__ ws)
{
    int t = blockIdx.x * blockDim.x + threadIdx.x;
    if (t >= 36 * 64) return;
    int f = t >> 6, l = t & 63, c = l & 15, q = l >> 4;
    unsigned short v[8] = {0, 0, 0, 0, 0, 0, 0, 0};
    const float* src = nullptr; int row = 0, k0 = 0, K = 0;
    if (f < 4) {
        if (q < 2) { src = W1; row = 16 * f + c; k0 = q * 8; K = 16; }
    } else if (f < 20) {
        int g = f - 4;  src = W2; row = 16 * (g >> 2) + c; k0 = (g & 3) * 32 + q * 8; K = 128;
    } else {
        int g = f - 20; src = W3; row = 16 * (g >> 2) + c; k0 = (g & 3) * 32 + q * 8; K = 128;
    }
    if (src) {
        #pragma unroll
        for (int j = 0; j < 8; ++j) v[j] = bfrne(src[row * K + k0 + j]);
    }
    unsigned short* dst = ws + (size_t)f * 512 + l * 8;
    *(ushort4*)(dst)     = make_ushort4(v[0], v[1], v[2], v[3]);
    *(ushort4*)(dst + 4) = make_ushort4(v[4], v[5], v[6], v[7]);
}

__global__ __launch_bounds__(256, 8) void fused_mlp_v6(
    const float* __restrict__ X, const int* __restrict__ M,
    const unsigned short* __restrict__ WF,
    const float* __restrict__ B1, const float* __restrict__ B2,
    const float* __restrict__ B3, float* __restrict__ OUT)
{
    __shared__ __align__(16) short sX[4][32 * kXS];  // 18432 B (single buffer)
    __shared__ __align__(16) short sP[4][64];        //   512 B

    const int t = threadIdx.x, w = t >> 6, l = t & 63, c = l & 15, q = l >> 4;
    const size_t bp = (size_t)blockIdx.x * 4 + w;

    short* xb = &sX[w][0];
    short* pl = &sP[w][0];

    // ---- inputs for this bp ----
    float4 xr[2][2];
    if (q < 2) {
        #pragma unroll
        for (int mt = 0; mt < 2; ++mt) {
            const float4* p = (const float4*)(X + (bp * 32 + 16 * mt + c) * 16 + q * 8);
            xr[mt][0] = p[0]; xr[mt][1] = p[1];
        }
    }
    const int4* Mp = (const int4*)(M + bp * 32);
    const int4 mr0 = Mp[q], mr1 = Mp[4 + q];
    const unsigned mbits =
        (mr0.x ? 1u : 0u)  | (mr0.y ? 2u : 0u)  | (mr0.z ? 4u : 0u)  | (mr0.w ? 8u : 0u) |
        (mr1.x ? 16u : 0u) | (mr1.y ? 32u : 0u) | (mr1.z ? 64u : 0u) | (mr1.w ? 128u : 0u);
    const bool anyv = __any(mbits != 0);

    // Pool-mask addends: invalid row -> -inf, so pool is max(pv, y+addm)
    // with no per-element cmp/cndmask. (8 VGPRs, live whole kernel.)
    float addm[8];
    #pragma unroll
    for (int i = 0; i < 8; ++i)
        addm[i] = ((mbits >> i) & 1u) ? 0.f : -INFINITY;

    float bias1[4];
    #pragma unroll
    for (int nt = 0; nt < 4; ++nt) bias1[nt] = B1[16 * nt + c];

    f32x4 acc[2][4];

    // ---- layer 1 (K=16 zero-padded to 32); W1 frags from WF ----
    {
        bf16x8 a1f[2];
        #pragma unroll
        for (int mt = 0; mt < 2; ++mt) {
            union { bf16x8 v; unsigned u[4]; } cv; cv.v = bf16x8{};
            if (q < 2) {
                cv.u[0] = cvtpk(xr[mt][0].x, xr[mt][0].y);
                cv.u[1] = cvtpk(xr[mt][0].z, xr[mt][0].w);
                cv.u[2] = cvtpk(xr[mt][1].x, xr[mt][1].y);
                cv.u[3] = cvtpk(xr[mt][1].z, xr[mt][1].w);
            }
            a1f[mt] = cv.v;
        }
        #pragma unroll
        for (int nt = 0; nt < 4; ++nt) {
            bf16x8 wf = *(const bf16x8*)(WF + (size_t)nt * 512 + l * 8);
            f32x4 c0 = { bias1[nt], bias1[nt], bias1[nt], bias1[nt] };
            acc[0][nt] = __builtin_amdgcn_mfma_f32_16x16x32_bf16(a1f[0], wf, c0, 0, 0, 0);
            acc[1][nt] = __builtin_amdgcn_mfma_f32_16x16x32_bf16(a1f[1], wf, c0, 0, 0, 0);
        }
    }

    // ---- epilogue: unmasked lrelu -> LDS (bf16 via cvt_pk), masked pool ----
    auto epilogue = [&](short* xb_, short* pl_) {
        float pool[4];
        #pragma unroll
        for (int nt = 0; nt < 4; ++nt) {
            float pv = -INFINITY;
            #pragma unroll
            for (int mt = 0; mt < 2; ++mt) {
                short* base = &xb_[(16 * mt + 4 * q) * kXS + 16 * nt + c];
                float y0 = lrelu(acc[mt][nt][0]);
                float y1 = lrelu(acc[mt][nt][1]);
                float y2 = lrelu(acc[mt][nt][2]);
                float y3 = lrelu(acc[mt][nt][3]);
                pv = fmaxf(pv, y0 + addm[mt * 4 + 0]);
                pv = fmaxf(pv, y1 + addm[mt * 4 + 1]);
                pv = fmaxf(pv, y2 + addm[mt * 4 + 2]);
                pv = fmaxf(pv, y3 + addm[mt * 4 + 3]);
                unsigned u01 = cvtpk(y0, y1);
                unsigned u23 = cvtpk(y2, y3);
                base[0 * kXS] = (short)u01;
                base[1 * kXS] = (short)(u01 >> 16);
                base[2 * kXS] = (short)u23;
                base[3 * kXS] = (short)(u23 >> 16);
            }
            pv = fmaxf(pv, __shfl_xor(pv, 16));
            pv = fmaxf(pv, __shfl_xor(pv, 32));
            pool[nt] = anyv ? pv : 0.f;
        }
        float ps = (q & 2) ? ((q & 1) ? pool[3] : pool[2])
                           : ((q & 1) ? pool[1] : pool[0]);
        pl_[16 * q + c] = (short)cvtpk(ps, ps);
    };

    // ---- K=128 layer: a-frags read per-ks (each feeds exactly one ks step,
    // keeps live VGPRs at 8 instead of 24); W-frags streamed from WF ----
    auto layerK = [&](const short* xb_, const short* pl_, int fb,
                      const float (&bias)[4]) {
        #pragma unroll
        for (int nt = 0; nt < 4; ++nt) {
            acc[0][nt] = f32x4{ bias[nt], bias[nt], bias[nt], bias[nt] };
            acc[1][nt] = acc[0][nt];
        }
        #pragma unroll
        for (int ks = 0; ks < 4; ++ks) {
            bf16x8 am0, am1;
            if (ks < 2) {
                am0 = *(const bf16x8*)&xb_[(     c) * kXS + ks * 32 + q * 8];
                am1 = *(const bf16x8*)&xb_[(16 + c) * kXS + ks * 32 + q * 8];
            } else {
                am0 = *(const bf16x8*)&pl_[(ks - 2) * 32 + q * 8];  // quad-bcast
                am1 = am0;
            }
            #pragma unroll
            for (int nt = 0; nt < 4; ++nt) {
                bf16x8 wf = *(const bf16x8*)(WF + ((size_t)(fb + nt * 4 + ks)) * 512 + l * 8);
                acc[0][nt] = __builtin_amdgcn_mfma_f32_16x16x32_bf16(am0, wf, acc[0][nt], 0, 0, 0);
                acc[1][nt] = __builtin_amdgcn_mfma_f32_16x16x32_bf16(am1, wf, acc[1][nt], 0, 0, 0);
            }
        }
    };

    epilogue(xb, pl);
    float bias2[4];
    #pragma unroll
    for (int nt = 0; nt < 4; ++nt) bias2[nt] = B2[16 * nt + c];
    layerK(xb, pl, 4, bias2);

    epilogue(xb, pl);
    float bias3[4];
    #pragma unroll
    for (int nt = 0; nt < 4; ++nt) bias3[nt] = B3[16 * nt + c];
    layerK(xb, pl, 20, bias3);

    // ---- layer-3 pool == final output ----
    {
        float pool[4];
        #pragma unroll
        for (int nt = 0; nt < 4; ++nt) {
            float pv = -INFINITY;
            #pragma unroll
            for (int mt = 0; mt < 2; ++mt)
                #pragma unroll
                for (int r = 0; r < 4; ++r)
                    pv = fmaxf(pv, lrelu(acc[mt][nt][r]) + addm[mt * 4 + r]);
            pv = fmaxf(pv, __shfl_xor(pv, 16));
            pv = fmaxf(pv, __shfl_xor(pv, 32));
            pool[nt] = anyv ? pv : 0.f;
        }
        float ps = (q & 2) ? ((q & 1) ? pool[3] : pool[2])
                           : ((q & 1) ? pool[1] : pool[0]);
        OUT[bp * 64 + 16 * q + c] = ps;
    }
}
} // namespace

extern "C" void kernel_launch(void* const* d_in, const int* in_sizes, int n_in,
                              void* d_out, int out_size, void* d_ws, size_t ws_size,
                              hipStream_t stream) {
    (void)in_sizes; (void)n_in; (void)ws_size; (void)out_size;
    const float* X  = (const float*)d_in[0];
    const int*   M  = (const int*)d_in[1];
    const float* W1 = (const float*)d_in[2];
    const float* B1 = (const float*)d_in[3];
    const float* W2 = (const float*)d_in[4];
    const float* B2 = (const float*)d_in[5];
    const float* W3 = (const float*)d_in[6];
    const float* B3 = (const float*)d_in[7];
    float* OUT = (float*)d_out;
    unsigned short* WF = (unsigned short*)d_ws;   // needs 36 KB of scratch

    prep_weights<<<(36 * 64 + 255) / 256, 256, 0, stream>>>(W1, W2, W3, WF);
    // 4096 blocks x 4 waves = 16384 waves; one bp per wave
    fused_mlp_v6<<<4096, 256, 0, stream>>>(X, M, WF, B1, B2, B3, OUT);
}

// Round 3
// 119.385 us; speedup vs baseline: 1.0674x; 1.0674x over previous
//
#include <hip/hip_runtime.h>
#include <math.h>

// (B,P,V,F,H) = (32,512,32,16,64). Round 7 resubmit (round-2 bench was an
// infra failure: container acquisition failed twice; no kernel signal).
// Round-6 lesson: __launch_bounds__(256,8) caps unified VGPR+AGPR at 64;
// kernel needs ~90 -> allocator spilled ~17 f32/lane to scratch = ~70 MB
// of HBM round-trips (WRITE_SIZE 4->53 MB) sitting on the serial
// layer->epilogue->layer chain. Occupancy gain and spill penalty cancelled.
// Fix: __launch_bounds__(256,6) (cap ~85) + drop the 16-reg xr staging
// array (cvt to bf16 a1f at load time) so actual usage fits the cap.
// Keeps round-6 wins: single LDS buffer/wave (18.9 KB -> 8 blocks/CU
// possible), pool masking via addm[]=0/-inf, v_cvt_pk_bf16_f32 packing,
// no per-element out-mask (final output depends only on pools; pools
// exclude masked rows, so unmasked lrelu values in LDS never surface).
// MFMA 16x16x32 bf16: A[m=lane&15][k=quad*8+j], B[k=quad*8+j][n=lane&15],
//                     D[row=quad*4+reg][col=lane&15]  (verified rounds 2-4).
namespace {
constexpr int kXS = 72;
constexpr float kSlope = 0.01f;

typedef short bf16x8 __attribute__((ext_vector_type(8)));
typedef float f32x4  __attribute__((ext_vector_type(4)));

__device__ __forceinline__ float lrelu(float x) { return fmaxf(x, kSlope * x); }

// 3-instruction round-to-nearest-even f32->bf16 (prep kernel only).
__device__ __forceinline__ unsigned short bfrne(float a) {
    union { float f; unsigned u; } v; v.f = a;
    return (unsigned short)((v.u + 0x7FFFu + ((v.u >> 16) & 1u)) >> 16);
}

// packed 2x f32 -> 2x bf16 (RNE), single VALU op. Non-volatile so the
// scheduler may move/CSE it freely.
__device__ __forceinline__ unsigned cvtpk(float lo, float hi) {
    unsigned r;
    asm("v_cvt_pk_bf16_f32 %0, %1, %2" : "=v"(r) : "v"(lo), "v"(hi));
    return r;
}

// ---- pre-pass: pack W1/W2/W3 as bf16 MFMA B-frags into d_ws ----
// frag f: 0..3 = W1 (nt=f, K=16 zero-padded); 4..19 = W2 (nt=(f-4)>>2,
// ks=(f-4)&3); 20..35 = W3. Lane l of frag f lives at ws[f*512 + l*8 ..+7].
__global__ void prep_weights(const float* __restrict__ W1,
                             const float* __restrict__ W2,
                             const float* __restrict__ W3,
                             unsigned short* __restrict__ ws)
{
    int t = blockIdx.x * blockDim.x + threadIdx.x;
    if (t >= 36 * 64) return;
    int f = t >> 6, l = t & 63, c = l & 15, q = l >> 4;
    unsigned short v[8] = {0, 0, 0, 0, 0, 0, 0, 0};
    const float* src = nullptr; int row = 0, k0 = 0, K = 0;
    if (f < 4) {
        if (q < 2) { src = W1; row = 16 * f + c; k0 = q * 8; K = 16; }
    } else if (f < 20) {
        int g = f - 4;  src = W2; row = 16 * (g >> 2) + c; k0 = (g & 3) * 32 + q * 8; K = 128;
    } else {
        int g = f - 20; src = W3; row = 16 * (g >> 2) + c; k0 = (g & 3) * 32 + q * 8; K = 128;
    }
    if (src) {
        #pragma unroll
        for (int j = 0; j < 8; ++j) v[j] = bfrne(src[row * K + k0 + j]);
    }
    unsigned short* dst = ws + (size_t)f * 512 + l * 8;
    *(ushort4*)(dst)     = make_ushort4(v[0], v[1], v[2], v[3]);
    *(ushort4*)(dst + 4) = make_ushort4(v[4], v[5], v[6], v[7]);
}

__global__ __launch_bounds__(256, 6) void fused_mlp_v7(
    const float* __restrict__ X, const int* __restrict__ M,
    const unsigned short* __restrict__ WF,
    const float* __restrict__ B1, const float* __restrict__ B2,
    const float* __restrict__ B3, float* __restrict__ OUT)
{
    __shared__ __align__(16) short sX[4][32 * kXS];  // 18432 B (single buffer)
    __shared__ __align__(16) short sP[4][64];        //   512 B

    const int t = threadIdx.x, w = t >> 6, l = t & 63, c = l & 15, q = l >> 4;
    const size_t bp = (size_t)blockIdx.x * 4 + w;

    short* xb = &sX[w][0];
    short* pl = &sP[w][0];

    // ---- inputs for this bp: load + convert immediately (a1f replaces the
    // old 16-reg xr staging array; halves prologue register liveness) ----
    bf16x8 a1f[2];
    #pragma unroll
    for (int mt = 0; mt < 2; ++mt) {
        union { bf16x8 v; unsigned u[4]; } cv; cv.v = bf16x8{};
        if (q < 2) {
            const float4* p = (const float4*)(X + (bp * 32 + 16 * mt + c) * 16 + q * 8);
            float4 f0 = p[0], f1 = p[1];
            cv.u[0] = cvtpk(f0.x, f0.y);
            cv.u[1] = cvtpk(f0.z, f0.w);
            cv.u[2] = cvtpk(f1.x, f1.y);
            cv.u[3] = cvtpk(f1.z, f1.w);
        }
        a1f[mt] = cv.v;
    }
    const int4* Mp = (const int4*)(M + bp * 32);
    const int4 mr0 = Mp[q], mr1 = Mp[4 + q];
    const unsigned mbits =
        (mr0.x ? 1u : 0u)  | (mr0.y ? 2u : 0u)  | (mr0.z ? 4u : 0u)  | (mr0.w ? 8u : 0u) |
        (mr1.x ? 16u : 0u) | (mr1.y ? 32u : 0u) | (mr1.z ? 64u : 0u) | (mr1.w ? 128u : 0u);
    const bool anyv = __any(mbits != 0);

    // Pool-mask addends: invalid row -> -inf, so pool is max(pv, y+addm)
    // with no per-element cmp/cndmask. (8 VGPRs; compiler may rematerialize
    // or spill these across layerK — they're epilogue-only.)
    float addm[8];
    #pragma unroll
    for (int i = 0; i < 8; ++i)
        addm[i] = ((mbits >> i) & 1u) ? 0.f : -INFINITY;

    f32x4 acc[2][4];

    // ---- layer 1 (K=16 zero-padded to 32); W1 frags from WF ----
    {
        #pragma unroll
        for (int nt = 0; nt < 4; ++nt) {
            float b1 = B1[16 * nt + c];
            bf16x8 wf = *(const bf16x8*)(WF + (size_t)nt * 512 + l * 8);
            f32x4 c0 = { b1, b1, b1, b1 };
            acc[0][nt] = __builtin_amdgcn_mfma_f32_16x16x32_bf16(a1f[0], wf, c0, 0, 0, 0);
            acc[1][nt] = __builtin_amdgcn_mfma_f32_16x16x32_bf16(a1f[1], wf, c0, 0, 0, 0);
        }
    }

    // ---- epilogue: unmasked lrelu -> LDS (bf16 via cvt_pk), masked pool ----
    auto epilogue = [&](short* xb_, short* pl_) {
        float pool[4];
        #pragma unroll
        for (int nt = 0; nt < 4; ++nt) {
            float pv = -INFINITY;
            #pragma unroll
            for (int mt = 0; mt < 2; ++mt) {
                short* base = &xb_[(16 * mt + 4 * q) * kXS + 16 * nt + c];
                float y0 = lrelu(acc[mt][nt][0]);
                float y1 = lrelu(acc[mt][nt][1]);
                float y2 = lrelu(acc[mt][nt][2]);
                float y3 = lrelu(acc[mt][nt][3]);
                pv = fmaxf(pv, y0 + addm[mt * 4 + 0]);
                pv = fmaxf(pv, y1 + addm[mt * 4 + 1]);
                pv = fmaxf(pv, y2 + addm[mt * 4 + 2]);
                pv = fmaxf(pv, y3 + addm[mt * 4 + 3]);
                unsigned u01 = cvtpk(y0, y1);
                unsigned u23 = cvtpk(y2, y3);
                base[0 * kXS] = (short)u01;
                base[1 * kXS] = (short)(u01 >> 16);
                base[2 * kXS] = (short)u23;
                base[3 * kXS] = (short)(u23 >> 16);
            }
            pv = fmaxf(pv, __shfl_xor(pv, 16));
            pv = fmaxf(pv, __shfl_xor(pv, 32));
            pool[nt] = anyv ? pv : 0.f;
        }
        float ps = (q & 2) ? ((q & 1) ? pool[3] : pool[2])
                           : ((q & 1) ? pool[1] : pool[0]);
        pl_[16 * q + c] = (short)cvtpk(ps, ps);
    };

    // ---- K=128 layer: a-frags read per-ks (each feeds exactly one ks step,
    // keeps live VGPRs at 8 instead of 24); W-frags streamed from WF ----
    auto layerK = [&](const short* xb_, const short* pl_, int fb,
                      const float* Bp) {
        #pragma unroll
        for (int nt = 0; nt < 4; ++nt) {
            float bb = Bp[16 * nt + c];
            acc[0][nt] = f32x4{ bb, bb, bb, bb };
            acc[1][nt] = acc[0][nt];
        }
        #pragma unroll
        for (int ks = 0; ks < 4; ++ks) {
            bf16x8 am0, am1;
            if (ks < 2) {
                am0 = *(const bf16x8*)&xb_[(     c) * kXS + ks * 32 + q * 8];
                am1 = *(const bf16x8*)&xb_[(16 + c) * kXS + ks * 32 + q * 8];
            } else {
                am0 = *(const bf16x8*)&pl_[(ks - 2) * 32 + q * 8];  // quad-bcast
                am1 = am0;
            }
            #pragma unroll
            for (int nt = 0; nt < 4; ++nt) {
                bf16x8 wf = *(const bf16x8*)(WF + ((size_t)(fb + nt * 4 + ks)) * 512 + l * 8);
                acc[0][nt] = __builtin_amdgcn_mfma_f32_16x16x32_bf16(am0, wf, acc[0][nt], 0, 0, 0);
                acc[1][nt] = __builtin_amdgcn_mfma_f32_16x16x32_bf16(am1, wf, acc[1][nt], 0, 0, 0);
            }
        }
    };

    epilogue(xb, pl);
    layerK(xb, pl, 4, B2);

    epilogue(xb, pl);
    layerK(xb, pl, 20, B3);

    // ---- layer-3 pool == final output ----
    {
        float pool[4];
        #pragma unroll
        for (int nt = 0; nt < 4; ++nt) {
            float pv = -INFINITY;
            #pragma unroll
            for (int mt = 0; mt < 2; ++mt)
                #pragma unroll
                for (int r = 0; r < 4; ++r)
                    pv = fmaxf(pv, lrelu(acc[mt][nt][r]) + addm[mt * 4 + r]);
            pv = fmaxf(pv, __shfl_xor(pv, 16));
            pv = fmaxf(pv, __shfl_xor(pv, 32));
            pool[nt] = anyv ? pv : 0.f;
        }
        float ps = (q & 2) ? ((q & 1) ? pool[3] : pool[2])
                           : ((q & 1) ? pool[1] : pool[0]);
        OUT[bp * 64 + 16 * q + c] = ps;
    }
}
} // namespace

extern "C" void kernel_launch(void* const* d_in, const int* in_sizes, int n_in,
                              void* d_out, int out_size, void* d_ws, size_t ws_size,
                              hipStream_t stream) {
    (void)in_sizes; (void)n_in; (void)ws_size; (void)out_size;
    const float* X  = (const float*)d_in[0];
    const int*   M  = (const int*)d_in[1];
    const float* W1 = (const float*)d_in[2];
    const float* B1 = (const float*)d_in[3];
    const float* W2 = (const float*)d_in[4];
    const float* B2 = (const float*)d_in[5];
    const float* W3 = (const float*)d_in[6];
    const float* B3 = (const float*)d_in[7];
    float* OUT = (float*)d_out;
    unsigned short* WF = (unsigned short*)d_ws;   // needs 36 KB of scratch

    prep_weights<<<(36 * 64 + 255) / 256, 256, 0, stream>>>(W1, W2, W3, WF);
    // 4096 blocks x 4 waves = 16384 waves; one bp per wave
    fused_mlp_v7<<<4096, 256, 0, stream>>>(X, M, WF, B1, B2, B3, OUT);
}